// Round 6
// baseline (144.346 us; speedup 1.0000x reference)
//
#include <hip/hip_runtime.h>
#include <float.h>

using v2f = __attribute__((ext_vector_type(2))) float;
using v4f = __attribute__((ext_vector_type(4))) float;

#define EMB 10
#define STATE 20
#define HIDDEN 40
#define NPROJ 2490
#define WAVES 16
#define ITEMS 128           // items per scan block = 64 lanes x IPL(2)

// Forced packed-f32 codegen: one VOP3P per 2 FMAs, table operand direct from
// SGPR pair (s_load path), weights in VGPR pair. D = S0*S1 + S2.
#define PK_MUL(acc, s, w) \
    asm("v_pk_mul_f32 %0, %1, %2" : "=v"(acc) : "s"(s), "v"(w))
#define PK_FMA(acc, s, w) \
    asm("v_pk_fma_f32 %0, %1, %2, %0" : "+v"(acc) : "s"(s), "v"(w))

// ============================ MLP kernel =================================
// One thread = one item. Writes the 10 layer-2 outputs per item to ws.
__global__ __launch_bounds__(256, 4) void mlp_kernel(
    const int* __restrict__ wid, const int* __restrict__ pid,
    const float* __restrict__ wemb, const float* __restrict__ pemb,
    const float* __restrict__ W1, const float* __restrict__ b1,
    const float* __restrict__ W2, const float* __restrict__ b2,
    float* __restrict__ ws)
{
    const int b = blockIdx.x * 256 + threadIdx.x;

    const int wi = wid[b];
    const int pi = pid[b];
    const float* __restrict__ wr = wemb + wi * EMB;
    const float* __restrict__ pr = pemb + pi * EMB;
    v2f x2[STATE / 2];
    #pragma unroll
    for (int k = 0; k < EMB / 2; ++k) x2[k] = *(const v2f*)(wr + 2 * k);
    #pragma unroll
    for (int k = 0; k < EMB / 2; ++k) x2[EMB / 2 + k] = *(const v2f*)(pr + 2 * k);

    float hb[HIDDEN];
    #pragma unroll 4
    for (int j = 0; j < HIDDEN; ++j) {
        const v2f* w1r = (const v2f*)(W1 + j * STATE);
        v2f a = w1r[0] * x2[0];
        #pragma unroll
        for (int k = 1; k < STATE / 2; ++k) a += w1r[k] * x2[k];
        hb[j] = fmaxf(a.x + a.y + b1[j], 0.0f);
    }
    v2f h2[HIDDEN / 2];
    #pragma unroll
    for (int k = 0; k < HIDDEN / 2; ++k) h2[k] = (v2f){hb[2 * k], hb[2 * k + 1]};

    v2f* wout = (v2f*)(ws + b * EMB);
    #pragma unroll
    for (int d = 0; d < EMB; d += 2) {
        const v2f* w2r0 = (const v2f*)(W2 + d * HIDDEN);
        const v2f* w2r1 = (const v2f*)(W2 + (d + 1) * HIDDEN);
        v2f a0 = w2r0[0] * h2[0];
        v2f a1 = w2r1[0] * h2[0];
        #pragma unroll
        for (int k = 1; k < HIDDEN / 2; ++k) { a0 += w2r0[k] * h2[k]; a1 += w2r1[k] * h2[k]; }
        wout[d / 2] = (v2f){a0.x + a0.y + b2[d], a1.x + a1.y + b2[d + 1]};
    }
}

// ============================ scan kernel ================================
// Score one even-aligned row pair (rows 2p, 2p+1) for TWO items per lane.
// tp (double* into pemb) is wave-uniform -> s_load_dwordx2/x8; each asm op is
// one v_pk_fma_f32 (2 FMAs). Accumulation order is bitwise-identical to the
// previous HIP version: even/odd chains per row, then horizontal add.
__device__ __forceinline__ void score_pair2(const double* __restrict__ tp, int p,
                                            const v2f wv[2][5],
                                            float best[2], int bidx[2]) {
    double d0 = tp[0], d1 = tp[1], d2 = tp[2], d3 = tp[3], d4 = tp[4];
    double d5 = tp[5], d6 = tp[6], d7 = tp[7], d8 = tp[8], d9 = tp[9];
    #pragma unroll
    for (int g = 0; g < 2; ++g) {
        v2f c0, c1;
        PK_MUL(c0, d0, wv[g][0]);
        PK_FMA(c0, d1, wv[g][1]);
        PK_FMA(c0, d2, wv[g][2]);
        PK_FMA(c0, d3, wv[g][3]);
        PK_FMA(c0, d4, wv[g][4]);
        float s0 = c0.x + c0.y;
        PK_MUL(c1, d5, wv[g][0]);
        PK_FMA(c1, d6, wv[g][1]);
        PK_FMA(c1, d7, wv[g][2]);
        PK_FMA(c1, d8, wv[g][3]);
        PK_FMA(c1, d9, wv[g][4]);
        float s1 = c1.x + c1.y;
        float sp = s0; int ip = 2 * p;
        if (s1 > sp) { sp = s1; ip = 2 * p + 1; }   // strict > : earlier index wins
        if (sp > best[g]) { best[g] = sp; bidx[g] = ip; }
    }
}

// Constant bounds -> p provably uniform -> deep s_load pipelining.
template <int P0, int P1>
__device__ __forceinline__ void scan_range(const double* __restrict__ tbl8,
                                           const v2f wv[2][5],
                                           float best[2], int bidx[2]) {
    const double* tp = tbl8 + P0 * 10;
    #pragma unroll 4
    for (int p = P0; p < P1; ++p, tp += 10) score_pair2(tp, p, wv, best, bidx);
}

// 1024 threads = 16 waves, 128 items per block (lane l owns items l, 64+l).
// No MLP phase: wv comes straight from ws (L2-resident). Wave w scans
// constant-bound slice w; one barrier for the final reduce.
__global__ __launch_bounds__(1024, 8) void scan_kernel(
    const float* __restrict__ pemb, const float* __restrict__ ws,
    int* __restrict__ out)
{
    __shared__ float sb[WAVES][ITEMS];  // per-slice partial best (8 KB)
    __shared__ int   si[WAVES][ITEMS];  // per-slice partial argmax (8 KB)

    const int tid  = threadIdx.x;
    const int lane = tid & 63;
    const int wave = tid >> 6;
    const int itemBase = blockIdx.x * ITEMS;

    const double* __restrict__ tbl8 =
        (const double*)__builtin_assume_aligned(pemb, 8);

    // ---- each lane loads weights for its 2 items from workspace ----
    v2f wv[2][5];
    #pragma unroll
    for (int g = 0; g < 2; ++g) {
        const v2f* src = (const v2f*)(ws + (itemBase + g * 64 + lane) * EMB);
        #pragma unroll
        for (int k = 0; k < 5; ++k) wv[g][k] = src[k];
    }

    float best[2];
    int   bidx[2];
    #pragma unroll
    for (int g = 0; g < 2; ++g) { best[g] = -FLT_MAX; bidx[g] = 1; }

    if (wave == 0) {
        // row 1 alone (row 0 excluded from the table): 8B-aligned loads
        v2f c0v = *(const v2f*)(pemb + 10);
        v4f c1v = *(const v4f*)(pemb + 12);
        v4f c2v = *(const v4f*)(pemb + 16);
        #pragma unroll
        for (int g = 0; g < 2; ++g) {
            v2f a = wv[g][0] * c0v;
            a += wv[g][1] * c1v.lo; a += wv[g][2] * c1v.hi;
            a += wv[g][3] * c2v.lo; a += wv[g][4] * c2v.hi;
            best[g] = a.x + a.y; bidx[g] = 1;
        }
    }

    // pairs p in [1,1245): rows (2p,2p+1). 1244 pairs, 16 constant-bound
    // slices in ascending order (slices 0-11: 78 pairs, 12-15: 77 pairs).
    switch (wave) {
        case  0: scan_range<   1,   79>(tbl8, wv, best, bidx); break;
        case  1: scan_range<  79,  157>(tbl8, wv, best, bidx); break;
        case  2: scan_range< 157,  235>(tbl8, wv, best, bidx); break;
        case  3: scan_range< 235,  313>(tbl8, wv, best, bidx); break;
        case  4: scan_range< 313,  391>(tbl8, wv, best, bidx); break;
        case  5: scan_range< 391,  469>(tbl8, wv, best, bidx); break;
        case  6: scan_range< 469,  547>(tbl8, wv, best, bidx); break;
        case  7: scan_range< 547,  625>(tbl8, wv, best, bidx); break;
        case  8: scan_range< 625,  703>(tbl8, wv, best, bidx); break;
        case  9: scan_range< 703,  781>(tbl8, wv, best, bidx); break;
        case 10: scan_range< 781,  859>(tbl8, wv, best, bidx); break;
        case 11: scan_range< 859,  937>(tbl8, wv, best, bidx); break;
        case 12: scan_range< 937, 1014>(tbl8, wv, best, bidx); break;
        case 13: scan_range<1014, 1091>(tbl8, wv, best, bidx); break;
        case 14: scan_range<1091, 1168>(tbl8, wv, best, bidx); break;
        case 15: scan_range<1168, 1245>(tbl8, wv, best, bidx); break;
    }

    // ---- write per-slice partials (ascending slice -> strict > keeps ties) ----
    #pragma unroll
    for (int g = 0; g < 2; ++g) {
        sb[wave][g * 64 + lane] = best[g];
        si[wave][g * 64 + lane] = bidx[g];
    }
    __syncthreads();

    if (tid < ITEMS) {
        float bb = sb[0][tid];
        int   bi = si[0][tid];
        #pragma unroll
        for (int w = 1; w < WAVES; ++w) {
            float v  = sb[w][tid];
            int   vi = si[w][tid];
            if (v > bb) { bb = v; bi = vi; }
        }
        out[itemBase + tid] = bi;
    }
}

// ==================== fallback (single-kernel, proven) ====================
__global__ __launch_bounds__(1024, 8) void actor_kernel(
    const int* __restrict__ wid, const int* __restrict__ pid,
    const float* __restrict__ wemb, const float* __restrict__ pemb,
    const float* __restrict__ W1, const float* __restrict__ b1,
    const float* __restrict__ W2, const float* __restrict__ b2,
    int* __restrict__ out)
{
    __shared__ v2f   sw[ITEMS][5];
    __shared__ float sb[WAVES][ITEMS];
    __shared__ int   si[WAVES][ITEMS];

    const int tid  = threadIdx.x;
    const int lane = tid & 63;
    const int wave = tid >> 6;
    const int itemBase = blockIdx.x * ITEMS;

    const double* __restrict__ tbl8 =
        (const double*)__builtin_assume_aligned(pemb, 8);

    if (wave < ITEMS / 64) {
        const int b = itemBase + wave * 64 + lane;
        const int wi = wid[b];
        const int pi = pid[b];
        const float* __restrict__ wr = wemb + wi * EMB;
        const float* __restrict__ pr = pemb + pi * EMB;
        v2f x2[STATE / 2];
        #pragma unroll
        for (int k = 0; k < EMB / 2; ++k) x2[k] = *(const v2f*)(wr + 2 * k);
        #pragma unroll
        for (int k = 0; k < EMB / 2; ++k) x2[EMB / 2 + k] = *(const v2f*)(pr + 2 * k);

        float hb[HIDDEN];
        #pragma unroll 4
        for (int j = 0; j < HIDDEN; ++j) {
            const v2f* w1r = (const v2f*)(W1 + j * STATE);
            v2f a = w1r[0] * x2[0];
            #pragma unroll
            for (int k = 1; k < STATE / 2; ++k) a += w1r[k] * x2[k];
            hb[j] = fmaxf(a.x + a.y + b1[j], 0.0f);
        }
        v2f h2[HIDDEN / 2];
        #pragma unroll
        for (int k = 0; k < HIDDEN / 2; ++k) h2[k] = (v2f){hb[2 * k], hb[2 * k + 1]};

        #pragma unroll
        for (int d = 0; d < EMB; d += 2) {
            const v2f* w2r0 = (const v2f*)(W2 + d * HIDDEN);
            const v2f* w2r1 = (const v2f*)(W2 + (d + 1) * HIDDEN);
            v2f a0 = w2r0[0] * h2[0];
            v2f a1 = w2r1[0] * h2[0];
            #pragma unroll
            for (int k = 1; k < HIDDEN / 2; ++k) { a0 += w2r0[k] * h2[k]; a1 += w2r1[k] * h2[k]; }
            sw[wave * 64 + lane][d / 2] = (v2f){a0.x + a0.y + b2[d], a1.x + a1.y + b2[d + 1]};
        }
    }
    __syncthreads();

    v2f wv[2][5];
    #pragma unroll
    for (int g = 0; g < 2; ++g) {
        #pragma unroll
        for (int k = 0; k < 5; ++k) wv[g][k] = sw[g * 64 + lane][k];
    }

    float best[2];
    int   bidx[2];
    #pragma unroll
    for (int g = 0; g < 2; ++g) { best[g] = -FLT_MAX; bidx[g] = 1; }

    if (wave == 0) {
        v2f c0v = *(const v2f*)(pemb + 10);
        v4f c1v = *(const v4f*)(pemb + 12);
        v4f c2v = *(const v4f*)(pemb + 16);
        #pragma unroll
        for (int g = 0; g < 2; ++g) {
            v2f a = wv[g][0] * c0v;
            a += wv[g][1] * c1v.lo; a += wv[g][2] * c1v.hi;
            a += wv[g][3] * c2v.lo; a += wv[g][4] * c2v.hi;
            best[g] = a.x + a.y; bidx[g] = 1;
        }
    }

    int start = (wave < 12) ? (1 + 78 * wave) : (937 + 77 * (wave - 12));
    int cnt   = (wave < 12) ? 78 : 77;
    start = __builtin_amdgcn_readfirstlane(start);
    cnt   = __builtin_amdgcn_readfirstlane(cnt);

    const double* tp = tbl8 + start * 10;
    #pragma unroll 4
    for (int i = 0; i < cnt; ++i, tp += 10)
        score_pair2(tp, start + i, wv, best, bidx);

    #pragma unroll
    for (int g = 0; g < 2; ++g) {
        sb[wave][g * 64 + lane] = best[g];
        si[wave][g * 64 + lane] = bidx[g];
    }
    __syncthreads();

    if (tid < ITEMS) {
        float bb = sb[0][tid];
        int   bi = si[0][tid];
        #pragma unroll
        for (int w = 1; w < WAVES; ++w) {
            float v  = sb[w][tid];
            int   vi = si[w][tid];
            if (v > bb) { bb = v; bi = vi; }
        }
        out[itemBase + tid] = bi;
    }
}

extern "C" void kernel_launch(void* const* d_in, const int* in_sizes, int n_in,
                              void* d_out, int out_size, void* d_ws, size_t ws_size,
                              hipStream_t stream) {
    const int*   wid  = (const int*)  d_in[0];
    const int*   pid  = (const int*)  d_in[1];
    const float* wemb = (const float*)d_in[2];
    const float* pemb = (const float*)d_in[3];
    const float* W1   = (const float*)d_in[4];
    const float* b1   = (const float*)d_in[5];
    const float* W2   = (const float*)d_in[6];
    const float* b2   = (const float*)d_in[7];
    int* out = (int*)d_out;

    const int B = in_sizes[0];               // 65536
    const size_t ws_needed = (size_t)B * EMB * sizeof(float);   // 2.6 MB

    if (d_ws != nullptr && ws_size >= ws_needed) {
        float* ws = (float*)d_ws;
        mlp_kernel<<<B / 256, 256, 0, stream>>>(wid, pid, wemb, pemb, W1, b1, W2, b2, ws);
        scan_kernel<<<B / ITEMS, 1024, 0, stream>>>(pemb, ws, out);
    } else {
        actor_kernel<<<B / ITEMS, 1024, 0, stream>>>(wid, pid, wemb, pemb, W1, b1, W2, b2, out);
    }
}

// Round 7
// 133.704 us; speedup vs baseline: 1.0796x; 1.0796x over previous
//
#include <hip/hip_runtime.h>
#include <float.h>

using v2f = __attribute__((ext_vector_type(2))) float;
using v4f = __attribute__((ext_vector_type(4))) float;

#define EMB 10
#define STATE 20
#define HIDDEN 40
#define NPROJ 2490
#define WAVES 16
#define ITEMS 128           // items per scan block = 64 lanes x IPL(2)

// Split-K geometry: table pairs [1,1245) split into 2 halves of 622 pairs.
#define HALF_PAIRS 622
#define HALF_FLOATS (HALF_PAIRS * 20)   // 12440 floats = 49.76 KB
#define HALF_V4 (HALF_FLOATS / 4)       // 3110

// ============================ MLP kernel =================================
// One thread = one item. Writes the 10 layer-2 outputs per item to ws.
__global__ __launch_bounds__(256, 4) void mlp_kernel(
    const int* __restrict__ wid, const int* __restrict__ pid,
    const float* __restrict__ wemb, const float* __restrict__ pemb,
    const float* __restrict__ W1, const float* __restrict__ b1,
    const float* __restrict__ W2, const float* __restrict__ b2,
    float* __restrict__ ws)
{
    const int b = blockIdx.x * 256 + threadIdx.x;

    const int wi = wid[b];
    const int pi = pid[b];
    const float* __restrict__ wr = wemb + wi * EMB;
    const float* __restrict__ pr = pemb + pi * EMB;
    v2f x2[STATE / 2];
    #pragma unroll
    for (int k = 0; k < EMB / 2; ++k) x2[k] = *(const v2f*)(wr + 2 * k);
    #pragma unroll
    for (int k = 0; k < EMB / 2; ++k) x2[EMB / 2 + k] = *(const v2f*)(pr + 2 * k);

    float hb[HIDDEN];
    #pragma unroll 4
    for (int j = 0; j < HIDDEN; ++j) {
        const v2f* w1r = (const v2f*)(W1 + j * STATE);
        v2f a = w1r[0] * x2[0];
        #pragma unroll
        for (int k = 1; k < STATE / 2; ++k) a += w1r[k] * x2[k];
        hb[j] = fmaxf(a.x + a.y + b1[j], 0.0f);
    }
    v2f h2[HIDDEN / 2];
    #pragma unroll
    for (int k = 0; k < HIDDEN / 2; ++k) h2[k] = (v2f){hb[2 * k], hb[2 * k + 1]};

    v2f* wout = (v2f*)(ws + b * EMB);
    #pragma unroll
    for (int d = 0; d < EMB; d += 2) {
        const v2f* w2r0 = (const v2f*)(W2 + d * HIDDEN);
        const v2f* w2r1 = (const v2f*)(W2 + (d + 1) * HIDDEN);
        v2f a0 = w2r0[0] * h2[0];
        v2f a1 = w2r1[0] * h2[0];
        #pragma unroll
        for (int k = 1; k < HIDDEN / 2; ++k) { a0 += w2r0[k] * h2[k]; a1 += w2r1[k] * h2[k]; }
        wout[d / 2] = (v2f){a0.x + a0.y + b2[d], a1.x + a1.y + b2[d + 1]};
    }
}

// ===================== split-K LDS scan kernel ===========================
// Table half lives in LDS; ds_read_b128 at a wave-uniform address is a
// broadcast (no bank conflict) on the LGKM pipe, overlapping the VALU FMA
// chain -> removes the s_load/K$-miss stall (r5: VALUBusy 72%).
// Accumulation order per score is bitwise-identical to previous rounds.
template <int Q0, int Q1>
__device__ __forceinline__ void scan_lds_range(const v4f* lt4, int p2base,
                                               const v2f wv[2][5],
                                               float best[2], int bidx[2]) {
    #pragma unroll 4
    for (int q = Q0; q < Q1; ++q) {
        const v4f* tq = lt4 + q * 5;
        v4f a0 = tq[0], a1 = tq[1], a2 = tq[2], a3 = tq[3], a4 = tq[4];
        #pragma unroll
        for (int g = 0; g < 2; ++g) {
            v2f c0 = wv[g][0] * a0.lo;
            c0 += wv[g][1] * a0.hi; c0 += wv[g][2] * a1.lo;
            c0 += wv[g][3] * a1.hi; c0 += wv[g][4] * a2.lo;
            float s0 = c0.x + c0.y;
            v2f c1 = wv[g][0] * a2.hi;
            c1 += wv[g][1] * a3.lo; c1 += wv[g][2] * a3.hi;
            c1 += wv[g][3] * a4.lo; c1 += wv[g][4] * a4.hi;
            float s1 = c1.x + c1.y;
            float sp = s0; int ip = p2base + 2 * q;
            if (s1 > sp) { sp = s1; ip = p2base + 2 * q + 1; }  // strict >
            if (sp > best[g]) { best[g] = sp; bidx[g] = ip; }
        }
    }
}

// 512 threads = 8 waves. blockIdx.x = group*2 + half. Block covers 128 items
// (lane l owns items l, 64+l of its group) x one table half (622 pairs).
// 8 waves scan constant-bound slices of the half; partials -> workspace.
// LDS 57.9 KB static -> 2 blocks/CU.
__global__ __launch_bounds__(512, 4) void scan_split_kernel(
    const float* __restrict__ pemb, const float* __restrict__ wsW,
    float* __restrict__ wsF, int* __restrict__ wsI)
{
    __shared__ float lt[HALF_FLOATS];   // 49.76 KB table half
    __shared__ float sb[8][ITEMS];      // 4 KB
    __shared__ int   si[8][ITEMS];      // 4 KB

    const int tid   = threadIdx.x;
    const int lane  = tid & 63;
    const int wave  = tid >> 6;
    const int group = blockIdx.x >> 1;
    const int half  = blockIdx.x & 1;
    const int itemBase = group * ITEMS;

    // ---- per-lane weights for its 2 items (issued before staging) ----
    v2f wv[2][5];
    #pragma unroll
    for (int g = 0; g < 2; ++g) {
        const v2f* src = (const v2f*)(wsW + (itemBase + g * 64 + lane) * EMB);
        #pragma unroll
        for (int k = 0; k < 5; ++k) wv[g][k] = src[k];
    }

    // ---- stage this half's table rows into LDS (coalesced v4f) ----
    // half 0: rows [2,1246) = floats [20,12460); half 1: rows [1246,2490).
    const v4f* src4 = (const v4f*)(pemb + 20 + half * HALF_FLOATS);
    v4f* lt4w = (v4f*)lt;
    for (int j = tid; j < HALF_V4; j += 512) lt4w[j] = src4[j];
    __syncthreads();

    float best[2];
    int   bidx[2];
    #pragma unroll
    for (int g = 0; g < 2; ++g) { best[g] = -FLT_MAX; bidx[g] = 1; }

    const int p2base = 2 * (1 + HALF_PAIRS * half);   // uniform row base

    if (half == 0 && wave == 0) {
        // row 1 alone (row 0 excluded from the table): direct global reads
        v2f c0v = *(const v2f*)(pemb + 10);
        v4f c1v = *(const v4f*)(pemb + 12);
        v4f c2v = *(const v4f*)(pemb + 16);
        #pragma unroll
        for (int g = 0; g < 2; ++g) {
            v2f a = wv[g][0] * c0v;
            a += wv[g][1] * c1v.lo; a += wv[g][2] * c1v.hi;
            a += wv[g][3] * c2v.lo; a += wv[g][4] * c2v.hi;
            best[g] = a.x + a.y; bidx[g] = 1;
        }
    }

    // 622 local pairs, 8 constant-bound slices in ascending order
    // (waves 0-5: 78 pairs, waves 6-7: 77 pairs).
    const v4f* lt4 = (const v4f*)lt;
    switch (wave) {
        case 0: scan_lds_range<  0,  78>(lt4, p2base, wv, best, bidx); break;
        case 1: scan_lds_range< 78, 156>(lt4, p2base, wv, best, bidx); break;
        case 2: scan_lds_range<156, 234>(lt4, p2base, wv, best, bidx); break;
        case 3: scan_lds_range<234, 312>(lt4, p2base, wv, best, bidx); break;
        case 4: scan_lds_range<312, 390>(lt4, p2base, wv, best, bidx); break;
        case 5: scan_lds_range<390, 468>(lt4, p2base, wv, best, bidx); break;
        case 6: scan_lds_range<468, 545>(lt4, p2base, wv, best, bidx); break;
        case 7: scan_lds_range<545, 622>(lt4, p2base, wv, best, bidx); break;
    }

    // ---- block reduce (ascending wave -> strict > keeps first-max) ----
    #pragma unroll
    for (int g = 0; g < 2; ++g) {
        sb[wave][g * 64 + lane] = best[g];
        si[wave][g * 64 + lane] = bidx[g];
    }
    __syncthreads();

    if (tid < ITEMS) {
        float bb = sb[0][tid];
        int   bi = si[0][tid];
        #pragma unroll
        for (int w = 1; w < 8; ++w) {
            float v  = sb[w][tid];
            int   vi = si[w][tid];
            if (v > bb) { bb = v; bi = vi; }
        }
        wsF[group * 256 + half * ITEMS + tid] = bb;
        wsI[group * 256 + half * ITEMS + tid] = bi;
    }
}

// Combine the two half-table partials per item. Half 0 holds all lower row
// indices, so strict > keeps first-occurrence argmax semantics.
__global__ __launch_bounds__(256, 8) void combine_kernel(
    const float* __restrict__ wsF, const int* __restrict__ wsI,
    int* __restrict__ out)
{
    const int i = blockIdx.x * 256 + threadIdx.x;
    const int g = i >> 7;
    const int l = i & 127;
    const float a = wsF[g * 256 + l];
    const int  ai = wsI[g * 256 + l];
    const float bv = wsF[g * 256 + 128 + l];
    const int  bi = wsI[g * 256 + 128 + l];
    out[i] = (bv > a) ? bi : ai;
}

// ============ fallback 1: r5 two-kernel SMEM scan (proven 61.6us) =========
__device__ __forceinline__ void score_pair2(const v4f* __restrict__ tp, int p,
                                            const v2f wv[2][5],
                                            float best[2], int bidx[2]) {
    v4f a0 = tp[0], a1 = tp[1], a2 = tp[2], a3 = tp[3], a4 = tp[4];
    #pragma unroll
    for (int g = 0; g < 2; ++g) {
        v2f c0 = wv[g][0] * a0.lo;
        c0 += wv[g][1] * a0.hi; c0 += wv[g][2] * a1.lo;
        c0 += wv[g][3] * a1.hi; c0 += wv[g][4] * a2.lo;
        float s0 = c0.x + c0.y;
        v2f c1 = wv[g][0] * a2.hi;
        c1 += wv[g][1] * a3.lo; c1 += wv[g][2] * a3.hi;
        c1 += wv[g][3] * a4.lo; c1 += wv[g][4] * a4.hi;
        float s1 = c1.x + c1.y;
        float sp = s0; int ip = 2 * p;
        if (s1 > sp) { sp = s1; ip = 2 * p + 1; }
        if (sp > best[g]) { best[g] = sp; bidx[g] = ip; }
    }
}

template <int P0, int P1>
__device__ __forceinline__ void scan_range(const v4f* __restrict__ tbl4,
                                           const v2f wv[2][5],
                                           float best[2], int bidx[2]) {
    const v4f* tp = tbl4 + P0 * 5;
    #pragma unroll 4
    for (int p = P0; p < P1; ++p, tp += 5) score_pair2(tp, p, wv, best, bidx);
}

__global__ __launch_bounds__(1024, 8) void scan_kernel(
    const float* __restrict__ pemb, const float* __restrict__ ws,
    int* __restrict__ out)
{
    __shared__ float sb[WAVES][ITEMS];
    __shared__ int   si[WAVES][ITEMS];

    const int tid  = threadIdx.x;
    const int lane = tid & 63;
    const int wave = tid >> 6;
    const int itemBase = blockIdx.x * ITEMS;

    const v4f* __restrict__ tbl4 =
        (const v4f*)__builtin_assume_aligned(pemb, 16);

    v2f wv[2][5];
    #pragma unroll
    for (int g = 0; g < 2; ++g) {
        const v2f* src = (const v2f*)(ws + (itemBase + g * 64 + lane) * EMB);
        #pragma unroll
        for (int k = 0; k < 5; ++k) wv[g][k] = src[k];
    }

    float best[2];
    int   bidx[2];
    #pragma unroll
    for (int g = 0; g < 2; ++g) { best[g] = -FLT_MAX; bidx[g] = 1; }

    if (wave == 0) {
        v2f c0v = *(const v2f*)(pemb + 10);
        v4f c1v = *(const v4f*)(pemb + 12);
        v4f c2v = *(const v4f*)(pemb + 16);
        #pragma unroll
        for (int g = 0; g < 2; ++g) {
            v2f a = wv[g][0] * c0v;
            a += wv[g][1] * c1v.lo; a += wv[g][2] * c1v.hi;
            a += wv[g][3] * c2v.lo; a += wv[g][4] * c2v.hi;
            best[g] = a.x + a.y; bidx[g] = 1;
        }
    }

    switch (wave) {
        case  0: scan_range<   1,   79>(tbl4, wv, best, bidx); break;
        case  1: scan_range<  79,  157>(tbl4, wv, best, bidx); break;
        case  2: scan_range< 157,  235>(tbl4, wv, best, bidx); break;
        case  3: scan_range< 235,  313>(tbl4, wv, best, bidx); break;
        case  4: scan_range< 313,  391>(tbl4, wv, best, bidx); break;
        case  5: scan_range< 391,  469>(tbl4, wv, best, bidx); break;
        case  6: scan_range< 469,  547>(tbl4, wv, best, bidx); break;
        case  7: scan_range< 547,  625>(tbl4, wv, best, bidx); break;
        case  8: scan_range< 625,  703>(tbl4, wv, best, bidx); break;
        case  9: scan_range< 703,  781>(tbl4, wv, best, bidx); break;
        case 10: scan_range< 781,  859>(tbl4, wv, best, bidx); break;
        case 11: scan_range< 859,  937>(tbl4, wv, best, bidx); break;
        case 12: scan_range< 937, 1014>(tbl4, wv, best, bidx); break;
        case 13: scan_range<1014, 1091>(tbl4, wv, best, bidx); break;
        case 14: scan_range<1091, 1168>(tbl4, wv, best, bidx); break;
        case 15: scan_range<1168, 1245>(tbl4, wv, best, bidx); break;
    }

    #pragma unroll
    for (int g = 0; g < 2; ++g) {
        sb[wave][g * 64 + lane] = best[g];
        si[wave][g * 64 + lane] = bidx[g];
    }
    __syncthreads();

    if (tid < ITEMS) {
        float bb = sb[0][tid];
        int   bi = si[0][tid];
        #pragma unroll
        for (int w = 1; w < WAVES; ++w) {
            float v  = sb[w][tid];
            int   vi = si[w][tid];
            if (v > bb) { bb = v; bi = vi; }
        }
        out[itemBase + tid] = bi;
    }
}

// ================= fallback 2: r4 single-kernel (proven) ==================
__global__ __launch_bounds__(1024, 8) void actor_kernel(
    const int* __restrict__ wid, const int* __restrict__ pid,
    const float* __restrict__ wemb, const float* __restrict__ pemb,
    const float* __restrict__ W1, const float* __restrict__ b1,
    const float* __restrict__ W2, const float* __restrict__ b2,
    int* __restrict__ out)
{
    __shared__ v2f   sw[ITEMS][5];
    __shared__ float sb[WAVES][ITEMS];
    __shared__ int   si[WAVES][ITEMS];

    const int tid  = threadIdx.x;
    const int lane = tid & 63;
    const int wave = tid >> 6;
    const int itemBase = blockIdx.x * ITEMS;

    const v4f* __restrict__ tbl4 =
        (const v4f*)__builtin_assume_aligned(pemb, 16);

    if (wave < ITEMS / 64) {
        const int b = itemBase + wave * 64 + lane;
        const int wi = wid[b];
        const int pi = pid[b];
        const float* __restrict__ wr = wemb + wi * EMB;
        const float* __restrict__ pr = pemb + pi * EMB;
        v2f x2[STATE / 2];
        #pragma unroll
        for (int k = 0; k < EMB / 2; ++k) x2[k] = *(const v2f*)(wr + 2 * k);
        #pragma unroll
        for (int k = 0; k < EMB / 2; ++k) x2[EMB / 2 + k] = *(const v2f*)(pr + 2 * k);

        float hb[HIDDEN];
        #pragma unroll 4
        for (int j = 0; j < HIDDEN; ++j) {
            const v2f* w1r = (const v2f*)(W1 + j * STATE);
            v2f a = w1r[0] * x2[0];
            #pragma unroll
            for (int k = 1; k < STATE / 2; ++k) a += w1r[k] * x2[k];
            hb[j] = fmaxf(a.x + a.y + b1[j], 0.0f);
        }
        v2f h2[HIDDEN / 2];
        #pragma unroll
        for (int k = 0; k < HIDDEN / 2; ++k) h2[k] = (v2f){hb[2 * k], hb[2 * k + 1]};

        #pragma unroll
        for (int d = 0; d < EMB; d += 2) {
            const v2f* w2r0 = (const v2f*)(W2 + d * HIDDEN);
            const v2f* w2r1 = (const v2f*)(W2 + (d + 1) * HIDDEN);
            v2f a0 = w2r0[0] * h2[0];
            v2f a1 = w2r1[0] * h2[0];
            #pragma unroll
            for (int k = 1; k < HIDDEN / 2; ++k) { a0 += w2r0[k] * h2[k]; a1 += w2r1[k] * h2[k]; }
            sw[wave * 64 + lane][d / 2] = (v2f){a0.x + a0.y + b2[d], a1.x + a1.y + b2[d + 1]};
        }
    }
    __syncthreads();

    v2f wv[2][5];
    #pragma unroll
    for (int g = 0; g < 2; ++g) {
        #pragma unroll
        for (int k = 0; k < 5; ++k) wv[g][k] = sw[g * 64 + lane][k];
    }

    float best[2];
    int   bidx[2];
    #pragma unroll
    for (int g = 0; g < 2; ++g) { best[g] = -FLT_MAX; bidx[g] = 1; }

    if (wave == 0) {
        v2f c0v = *(const v2f*)(pemb + 10);
        v4f c1v = *(const v4f*)(pemb + 12);
        v4f c2v = *(const v4f*)(pemb + 16);
        #pragma unroll
        for (int g = 0; g < 2; ++g) {
            v2f a = wv[g][0] * c0v;
            a += wv[g][1] * c1v.lo; a += wv[g][2] * c1v.hi;
            a += wv[g][3] * c2v.lo; a += wv[g][4] * c2v.hi;
            best[g] = a.x + a.y; bidx[g] = 1;
        }
    }

    int start = (wave < 12) ? (1 + 78 * wave) : (937 + 77 * (wave - 12));
    int cnt   = (wave < 12) ? 78 : 77;
    start = __builtin_amdgcn_readfirstlane(start);
    cnt   = __builtin_amdgcn_readfirstlane(cnt);

    const v4f* tp = tbl4 + start * 5;
    #pragma unroll 4
    for (int i = 0; i < cnt; ++i, tp += 5)
        score_pair2(tp, start + i, wv, best, bidx);

    #pragma unroll
    for (int g = 0; g < 2; ++g) {
        sb[wave][g * 64 + lane] = best[g];
        si[wave][g * 64 + lane] = bidx[g];
    }
    __syncthreads();

    if (tid < ITEMS) {
        float bb = sb[0][tid];
        int   bi = si[0][tid];
        #pragma unroll
        for (int w = 1; w < WAVES; ++w) {
            float v  = sb[w][tid];
            int   vi = si[w][tid];
            if (v > bb) { bb = v; bi = vi; }
        }
        out[itemBase + tid] = bi;
    }
}

extern "C" void kernel_launch(void* const* d_in, const int* in_sizes, int n_in,
                              void* d_out, int out_size, void* d_ws, size_t ws_size,
                              hipStream_t stream) {
    const int*   wid  = (const int*)  d_in[0];
    const int*   pid  = (const int*)  d_in[1];
    const float* wemb = (const float*)d_in[2];
    const float* pemb = (const float*)d_in[3];
    const float* W1   = (const float*)d_in[4];
    const float* b1   = (const float*)d_in[5];
    const float* W2   = (const float*)d_in[6];
    const float* b2   = (const float*)d_in[7];
    int* out = (int*)d_out;

    const int B = in_sizes[0];               // 65536
    const int nGroups = B / ITEMS;           // 512

    const size_t wsW_bytes = (size_t)B * EMB * sizeof(float);       // 2,621,440
    const size_t wsF_bytes = (size_t)nGroups * 256 * sizeof(float); //   524,288
    const size_t wsI_bytes = (size_t)nGroups * 256 * sizeof(int);   //   524,288

    if (d_ws != nullptr && ws_size >= wsW_bytes + wsF_bytes + wsI_bytes) {
        float* wsW = (float*)d_ws;
        float* wsF = (float*)((char*)d_ws + wsW_bytes);
        int*   wsI = (int*)  ((char*)d_ws + wsW_bytes + wsF_bytes);
        mlp_kernel<<<B / 256, 256, 0, stream>>>(wid, pid, wemb, pemb, W1, b1, W2, b2, wsW);
        scan_split_kernel<<<nGroups * 2, 512, 0, stream>>>(pemb, wsW, wsF, wsI);
        combine_kernel<<<B / 256, 256, 0, stream>>>(wsF, wsI, out);
    } else if (d_ws != nullptr && ws_size >= wsW_bytes) {
        float* ws = (float*)d_ws;
        mlp_kernel<<<B / 256, 256, 0, stream>>>(wid, pid, wemb, pemb, W1, b1, W2, b2, ws);
        scan_kernel<<<B / ITEMS, 1024, 0, stream>>>(pemb, ws, out);
    } else {
        actor_kernel<<<B / ITEMS, 1024, 0, stream>>>(wid, pid, wemb, pemb, W1, b1, W2, b2, out);
    }
}

// Round 8
// 129.568 us; speedup vs baseline: 1.1141x; 1.0319x over previous
//
#include <hip/hip_runtime.h>
#include <float.h>

using v2f = __attribute__((ext_vector_type(2))) float;
using v4f = __attribute__((ext_vector_type(4))) float;

#define EMB 10
#define STATE 20
#define HIDDEN 40
#define NPROJ 2490
#define WAVES 16
#define ITEMS 128           // items per scan block = 64 lanes x IPL(2)

// ============================ MLP kernel =================================
// One thread = one item. Writes the 10 layer-2 outputs per item to ws.
__global__ __launch_bounds__(256, 4) void mlp_kernel(
    const int* __restrict__ wid, const int* __restrict__ pid,
    const float* __restrict__ wemb, const float* __restrict__ pemb,
    const float* __restrict__ W1, const float* __restrict__ b1,
    const float* __restrict__ W2, const float* __restrict__ b2,
    float* __restrict__ ws)
{
    const int b = blockIdx.x * 256 + threadIdx.x;

    const int wi = wid[b];
    const int pi = pid[b];
    const float* __restrict__ wr = wemb + wi * EMB;
    const float* __restrict__ pr = pemb + pi * EMB;
    v2f x2[STATE / 2];
    #pragma unroll
    for (int k = 0; k < EMB / 2; ++k) x2[k] = *(const v2f*)(wr + 2 * k);
    #pragma unroll
    for (int k = 0; k < EMB / 2; ++k) x2[EMB / 2 + k] = *(const v2f*)(pr + 2 * k);

    float hb[HIDDEN];
    #pragma unroll 4
    for (int j = 0; j < HIDDEN; ++j) {
        const v2f* w1r = (const v2f*)(W1 + j * STATE);
        v2f a = w1r[0] * x2[0];
        #pragma unroll
        for (int k = 1; k < STATE / 2; ++k) a += w1r[k] * x2[k];
        hb[j] = fmaxf(a.x + a.y + b1[j], 0.0f);
    }
    v2f h2[HIDDEN / 2];
    #pragma unroll
    for (int k = 0; k < HIDDEN / 2; ++k) h2[k] = (v2f){hb[2 * k], hb[2 * k + 1]};

    v2f* wout = (v2f*)(ws + b * EMB);
    #pragma unroll
    for (int d = 0; d < EMB; d += 2) {
        const v2f* w2r0 = (const v2f*)(W2 + d * HIDDEN);
        const v2f* w2r1 = (const v2f*)(W2 + (d + 1) * HIDDEN);
        v2f a0 = w2r0[0] * h2[0];
        v2f a1 = w2r1[0] * h2[0];
        #pragma unroll
        for (int k = 1; k < HIDDEN / 2; ++k) { a0 += w2r0[k] * h2[k]; a1 += w2r1[k] * h2[k]; }
        wout[d / 2] = (v2f){a0.x + a0.y + b2[d], a1.x + a1.y + b2[d + 1]};
    }
}

// ============================ scan kernel ================================
// PURE-SCALAR inner loop: table element t[k] is a wave-uniform scalar (SGPR);
// each v_fma_f32 reads it directly as its one legal SGPR operand -> no
// ext-vector lowering, no SGPR->VGPR moves, no hadds beyond the single e+o.
// Accumulation order is bitwise-identical to rounds 0-7: even-k chain +
// odd-k chain per row, then one add. Per-row direct compare vs best with
// uniform row index (strict >, earlier row checked first -> identical
// first-occurrence argmax semantics to the old tournament).
__device__ __forceinline__ void score_row(const float* __restrict__ tr, int row,
                                          const float w0[10], const float w1[10],
                                          float best[2], int bidx[2]) {
    float t0 = tr[0], t1 = tr[1], t2 = tr[2], t3 = tr[3], t4 = tr[4];
    float t5 = tr[5], t6 = tr[6], t7 = tr[7], t8 = tr[8], t9 = tr[9];

    float e0 = t0 * w0[0];
    float o0 = t1 * w0[1];
    e0 = fmaf(t2, w0[2], e0);  o0 = fmaf(t3, w0[3], o0);
    e0 = fmaf(t4, w0[4], e0);  o0 = fmaf(t5, w0[5], o0);
    e0 = fmaf(t6, w0[6], e0);  o0 = fmaf(t7, w0[7], o0);
    e0 = fmaf(t8, w0[8], e0);  o0 = fmaf(t9, w0[9], o0);
    float s0 = e0 + o0;

    float e1 = t0 * w1[0];
    float o1 = t1 * w1[1];
    e1 = fmaf(t2, w1[2], e1);  o1 = fmaf(t3, w1[3], o1);
    e1 = fmaf(t4, w1[4], e1);  o1 = fmaf(t5, w1[5], o1);
    e1 = fmaf(t6, w1[6], e1);  o1 = fmaf(t7, w1[7], o1);
    e1 = fmaf(t8, w1[8], e1);  o1 = fmaf(t9, w1[9], o1);
    float s1 = e1 + o1;

    if (s0 > best[0]) { best[0] = s0; bidx[0] = row; }
    if (s1 > best[1]) { best[1] = s1; bidx[1] = row; }
}

// Constant bounds -> p provably uniform -> scalar loads, deep pipelining.
template <int P0, int P1>
__device__ __forceinline__ void scan_range(const float* __restrict__ tblf,
                                           const float w0[10], const float w1[10],
                                           float best[2], int bidx[2]) {
    const float* t = tblf + P0 * 20;
    #pragma unroll 4
    for (int p = P0; p < P1; ++p, t += 20) {
        score_row(t,      2 * p,     w0, w1, best, bidx);
        score_row(t + 10, 2 * p + 1, w0, w1, best, bidx);
    }
}

// 1024 threads = 16 waves, 128 items per block (lane l owns items l, 64+l).
// No MLP phase: weights come straight from ws (L2-resident). Wave w scans
// constant-bound slice w; one barrier for the final reduce.
__global__ __launch_bounds__(1024, 8) void scan_kernel(
    const float* __restrict__ pemb, const float* __restrict__ ws,
    int* __restrict__ out)
{
    __shared__ float sb[WAVES][ITEMS];  // per-slice partial best (8 KB)
    __shared__ int   si[WAVES][ITEMS];  // per-slice partial argmax (8 KB)

    const int tid  = threadIdx.x;
    const int lane = tid & 63;
    const int wave = tid >> 6;
    const int itemBase = blockIdx.x * ITEMS;

    const float* __restrict__ tblf = pemb;   // row r at pemb + 20*p ... (pairs)

    // ---- per-lane weights for its 2 items (vector load, scalar extract) ----
    float w0[10], w1[10];
    {
        const v4f* s0 = (const v4f*)(ws + (itemBase + lane) * EMB);
        const v2f* s0t = (const v2f*)(ws + (itemBase + lane) * EMB + 8);
        v4f a = s0[0], b = s0[1]; v2f c = s0t[0];
        w0[0]=a.x; w0[1]=a.y; w0[2]=a.z; w0[3]=a.w;
        w0[4]=b.x; w0[5]=b.y; w0[6]=b.z; w0[7]=b.w;
        w0[8]=c.x; w0[9]=c.y;
        const v4f* s1 = (const v4f*)(ws + (itemBase + 64 + lane) * EMB);
        const v2f* s1t = (const v2f*)(ws + (itemBase + 64 + lane) * EMB + 8);
        v4f d = s1[0], e = s1[1]; v2f f = s1t[0];
        w1[0]=d.x; w1[1]=d.y; w1[2]=d.z; w1[3]=d.w;
        w1[4]=e.x; w1[5]=e.y; w1[6]=e.z; w1[7]=e.w;
        w1[8]=f.x; w1[9]=f.y;
    }

    float best[2];
    int   bidx[2];
    #pragma unroll
    for (int g = 0; g < 2; ++g) { best[g] = -FLT_MAX; bidx[g] = 1; }

    if (wave == 0) {
        // row 1 alone (row 0 excluded from the table)
        score_row(pemb + 10, 1, w0, w1, best, bidx);
    }

    // pairs p in [1,1245): rows (2p,2p+1). 1244 pairs, 16 constant-bound
    // slices in ascending order (slices 0-11: 78 pairs, 12-15: 77 pairs).
    switch (wave) {
        case  0: scan_range<   1,   79>(tblf, w0, w1, best, bidx); break;
        case  1: scan_range<  79,  157>(tblf, w0, w1, best, bidx); break;
        case  2: scan_range< 157,  235>(tblf, w0, w1, best, bidx); break;
        case  3: scan_range< 235,  313>(tblf, w0, w1, best, bidx); break;
        case  4: scan_range< 313,  391>(tblf, w0, w1, best, bidx); break;
        case  5: scan_range< 391,  469>(tblf, w0, w1, best, bidx); break;
        case  6: scan_range< 469,  547>(tblf, w0, w1, best, bidx); break;
        case  7: scan_range< 547,  625>(tblf, w0, w1, best, bidx); break;
        case  8: scan_range< 625,  703>(tblf, w0, w1, best, bidx); break;
        case  9: scan_range< 703,  781>(tblf, w0, w1, best, bidx); break;
        case 10: scan_range< 781,  859>(tblf, w0, w1, best, bidx); break;
        case 11: scan_range< 859,  937>(tblf, w0, w1, best, bidx); break;
        case 12: scan_range< 937, 1014>(tblf, w0, w1, best, bidx); break;
        case 13: scan_range<1014, 1091>(tblf, w0, w1, best, bidx); break;
        case 14: scan_range<1091, 1168>(tblf, w0, w1, best, bidx); break;
        case 15: scan_range<1168, 1245>(tblf, w0, w1, best, bidx); break;
    }

    // ---- write per-slice partials (ascending slice -> strict > keeps ties) ----
    sb[wave][lane]      = best[0];
    si[wave][lane]      = bidx[0];
    sb[wave][64 + lane] = best[1];
    si[wave][64 + lane] = bidx[1];
    __syncthreads();

    if (tid < ITEMS) {
        float bb = sb[0][tid];
        int   bi = si[0][tid];
        #pragma unroll
        for (int w = 1; w < WAVES; ++w) {
            float v  = sb[w][tid];
            int   vi = si[w][tid];
            if (v > bb) { bb = v; bi = vi; }
        }
        out[itemBase + tid] = bi;
    }
}

// ================= fallback: r4 single-kernel (proven) ====================
__device__ __forceinline__ void score_pair2(const v4f* __restrict__ tp, int p,
                                            const v2f wv[2][5],
                                            float best[2], int bidx[2]) {
    v4f a0 = tp[0], a1 = tp[1], a2 = tp[2], a3 = tp[3], a4 = tp[4];
    #pragma unroll
    for (int g = 0; g < 2; ++g) {
        v2f c0 = wv[g][0] * a0.lo;
        c0 += wv[g][1] * a0.hi; c0 += wv[g][2] * a1.lo;
        c0 += wv[g][3] * a1.hi; c0 += wv[g][4] * a2.lo;
        float s0 = c0.x + c0.y;
        v2f c1 = wv[g][0] * a2.hi;
        c1 += wv[g][1] * a3.lo; c1 += wv[g][2] * a3.hi;
        c1 += wv[g][3] * a4.lo; c1 += wv[g][4] * a4.hi;
        float s1 = c1.x + c1.y;
        float sp = s0; int ip = 2 * p;
        if (s1 > sp) { sp = s1; ip = 2 * p + 1; }
        if (sp > best[g]) { best[g] = sp; bidx[g] = ip; }
    }
}

__global__ __launch_bounds__(1024, 8) void actor_kernel(
    const int* __restrict__ wid, const int* __restrict__ pid,
    const float* __restrict__ wemb, const float* __restrict__ pemb,
    const float* __restrict__ W1, const float* __restrict__ b1,
    const float* __restrict__ W2, const float* __restrict__ b2,
    int* __restrict__ out)
{
    __shared__ v2f   sw[ITEMS][5];
    __shared__ float sb[WAVES][ITEMS];
    __shared__ int   si[WAVES][ITEMS];

    const int tid  = threadIdx.x;
    const int lane = tid & 63;
    const int wave = tid >> 6;
    const int itemBase = blockIdx.x * ITEMS;

    const v4f* __restrict__ tbl4 =
        (const v4f*)__builtin_assume_aligned(pemb, 16);

    if (wave < ITEMS / 64) {
        const int b = itemBase + wave * 64 + lane;
        const int wi = wid[b];
        const int pi = pid[b];
        const float* __restrict__ wr = wemb + wi * EMB;
        const float* __restrict__ pr = pemb + pi * EMB;
        v2f x2[STATE / 2];
        #pragma unroll
        for (int k = 0; k < EMB / 2; ++k) x2[k] = *(const v2f*)(wr + 2 * k);
        #pragma unroll
        for (int k = 0; k < EMB / 2; ++k) x2[EMB / 2 + k] = *(const v2f*)(pr + 2 * k);

        float hb[HIDDEN];
        #pragma unroll 4
        for (int j = 0; j < HIDDEN; ++j) {
            const v2f* w1r = (const v2f*)(W1 + j * STATE);
            v2f a = w1r[0] * x2[0];
            #pragma unroll
            for (int k = 1; k < STATE / 2; ++k) a += w1r[k] * x2[k];
            hb[j] = fmaxf(a.x + a.y + b1[j], 0.0f);
        }
        v2f h2[HIDDEN / 2];
        #pragma unroll
        for (int k = 0; k < HIDDEN / 2; ++k) h2[k] = (v2f){hb[2 * k], hb[2 * k + 1]};

        #pragma unroll
        for (int d = 0; d < EMB; d += 2) {
            const v2f* w2r0 = (const v2f*)(W2 + d * HIDDEN);
            const v2f* w2r1 = (const v2f*)(W2 + (d + 1) * HIDDEN);
            v2f a0 = w2r0[0] * h2[0];
            v2f a1 = w2r1[0] * h2[0];
            #pragma unroll
            for (int k = 1; k < HIDDEN / 2; ++k) { a0 += w2r0[k] * h2[k]; a1 += w2r1[k] * h2[k]; }
            sw[wave * 64 + lane][d / 2] = (v2f){a0.x + a0.y + b2[d], a1.x + a1.y + b2[d + 1]};
        }
    }
    __syncthreads();

    v2f wv[2][5];
    #pragma unroll
    for (int g = 0; g < 2; ++g) {
        #pragma unroll
        for (int k = 0; k < 5; ++k) wv[g][k] = sw[g * 64 + lane][k];
    }

    float best[2];
    int   bidx[2];
    #pragma unroll
    for (int g = 0; g < 2; ++g) { best[g] = -FLT_MAX; bidx[g] = 1; }

    if (wave == 0) {
        v2f c0v = *(const v2f*)(pemb + 10);
        v4f c1v = *(const v4f*)(pemb + 12);
        v4f c2v = *(const v4f*)(pemb + 16);
        #pragma unroll
        for (int g = 0; g < 2; ++g) {
            v2f a = wv[g][0] * c0v;
            a += wv[g][1] * c1v.lo; a += wv[g][2] * c1v.hi;
            a += wv[g][3] * c2v.lo; a += wv[g][4] * c2v.hi;
            best[g] = a.x + a.y; bidx[g] = 1;
        }
    }

    int start = (wave < 12) ? (1 + 78 * wave) : (937 + 77 * (wave - 12));
    int cnt   = (wave < 12) ? 78 : 77;
    start = __builtin_amdgcn_readfirstlane(start);
    cnt   = __builtin_amdgcn_readfirstlane(cnt);

    const v4f* tp = tbl4 + start * 5;
    #pragma unroll 4
    for (int i = 0; i < cnt; ++i, tp += 5)
        score_pair2(tp, start + i, wv, best, bidx);

    #pragma unroll
    for (int g = 0; g < 2; ++g) {
        sb[wave][g * 64 + lane] = best[g];
        si[wave][g * 64 + lane] = bidx[g];
    }
    __syncthreads();

    if (tid < ITEMS) {
        float bb = sb[0][tid];
        int   bi = si[0][tid];
        #pragma unroll
        for (int w = 1; w < WAVES; ++w) {
            float v  = sb[w][tid];
            int   vi = si[w][tid];
            if (v > bb) { bb = v; bi = vi; }
        }
        out[itemBase + tid] = bi;
    }
}

extern "C" void kernel_launch(void* const* d_in, const int* in_sizes, int n_in,
                              void* d_out, int out_size, void* d_ws, size_t ws_size,
                              hipStream_t stream) {
    const int*   wid  = (const int*)  d_in[0];
    const int*   pid  = (const int*)  d_in[1];
    const float* wemb = (const float*)d_in[2];
    const float* pemb = (const float*)d_in[3];
    const float* W1   = (const float*)d_in[4];
    const float* b1   = (const float*)d_in[5];
    const float* W2   = (const float*)d_in[6];
    const float* b2   = (const float*)d_in[7];
    int* out = (int*)d_out;

    const int B = in_sizes[0];               // 65536
    const size_t ws_needed = (size_t)B * EMB * sizeof(float);   // 2.6 MB

    if (d_ws != nullptr && ws_size >= ws_needed) {
        float* ws = (float*)d_ws;
        mlp_kernel<<<B / 256, 256, 0, stream>>>(wid, pid, wemb, pemb, W1, b1, W2, b2, ws);
        scan_kernel<<<B / ITEMS, 1024, 0, stream>>>(pemb, ws, out);
    } else {
        actor_kernel<<<B / ITEMS, 1024, 0, stream>>>(wid, pid, wemb, pemb, W1, b1, W2, b2, out);
    }
}